// Round 9
// baseline (174.364 us; speedup 1.0000x reference)
//
#include <hip/hip_runtime.h>
#include <hip/hip_bf16.h>
#include <stdint.h>

// LSTM cell fused, four-kernel version (R9: 128x128 tiles, 4 blocks/CU TLP):
//   pack:    weights -> bf16 MFMA-B-fragment layout, col-groups of 128
//            (gate-major within 64-col wave slices); bias packed likewise
//   convert: X=[input|hidden] f32 -> bf16 in A-fragment glds order (64 MB,
//            stored in d_out[0:BH) which is free until K2 overwrites it)
//   K1:      gates GEMM, 128x128 tile, 4 waves, dbuf 32KB LDS, pure glds
//            staging, 1 barrier/step, setprio. 4 blocks/CU -> 4 independent
//            barrier domains hide each other's stalls.
//   K2:      per-row log_softmax finalize -> writes output 0
// B=65536, IN=H=256, K=512, 4H=1024 gate cols.

#define BH 16777216  // 65536*256

typedef float f32x4 __attribute__((ext_vector_type(4)));
typedef short short8 __attribute__((ext_vector_type(8)));

__device__ __forceinline__ unsigned short f2bf(float f) {
    union { float f; unsigned u; } v; v.f = f;
    unsigned u = v.u;
    return (unsigned short)((u + 0x7fffu + ((u >> 16) & 1u)) >> 16);
}

__device__ __forceinline__ unsigned pack2bf(float a, float b) {
    __hip_bfloat162 h = __float22bfloat162_rn(make_float2(a, b));
    union { __hip_bfloat162 h; unsigned u; } v; v.h = h;
    return v.u;  // v_cvt_pk_bf16_f32
}

__device__ __forceinline__ float sigm(float x) { return 1.f / (1.f + __expf(-x)); }
__device__ __forceinline__ float tanh_(float x) { return 1.f - 2.f / (1.f + __expf(2.f * x)); }

__device__ __forceinline__ void glds16(const void* g, const void* l) {
    __builtin_amdgcn_global_load_lds(
        (const __attribute__((address_space(1))) unsigned int*)(uintptr_t)g,
        (__attribute__((address_space(3))) unsigned int*)(unsigned int)(uintptr_t)l,
        16, 0, 0);
}

// ---- pack: wpack[cg(8)][step(16)][Nt8(8)][lane(64)][j(8)] bf16 ----
// packed col cp = cg*128 + Nt8*16 + n16 ; Nt8 = wn2*4 + gate ;
// h = cg*32 + wn2*16 + n16 ; value = W[gate][h][k], k = step*32+(l>>4)*8+j
__global__ __launch_bounds__(256) void pack_kernel(
    const float* __restrict__ Wif, const float* __restrict__ Wii,
    const float* __restrict__ Wio, const float* __restrict__ Wig,
    const float* __restrict__ Whf, const float* __restrict__ Whi,
    const float* __restrict__ Who, const float* __restrict__ Whg,
    const float* __restrict__ bif, const float* __restrict__ bii,
    const float* __restrict__ bio, const float* __restrict__ big,
    const float* __restrict__ bhf, const float* __restrict__ bhi,
    const float* __restrict__ bho, const float* __restrict__ bhg,
    unsigned short* __restrict__ wpack, float* __restrict__ bpack)
{
    const int t = blockIdx.x * 256 + threadIdx.x;   // 0..65535
    const int l    = t & 63;
    const int Nt8  = (t >> 6) & 7;
    const int step = (t >> 9) & 15;
    const int cg   = t >> 13;                        // 0..7
    const int gate = Nt8 & 3;
    const int wn2  = Nt8 >> 2;
    const int h    = cg * 32 + wn2 * 16 + (l & 15);
    const int k0   = step * 32 + (l >> 4) * 8;

    const float* Wi = (gate == 0) ? Wif : (gate == 1) ? Wii : (gate == 2) ? Wio : Wig;
    const float* Wh = (gate == 0) ? Whf : (gate == 1) ? Whi : (gate == 2) ? Who : Whg;
    const float* src = (k0 < 256) ? (Wi + h * 256 + k0) : (Wh + h * 256 + (k0 - 256));

    unsigned pk[4];
#pragma unroll
    for (int p = 0; p < 4; ++p)
        pk[p] = (unsigned)f2bf(src[p * 2]) | ((unsigned)f2bf(src[p * 2 + 1]) << 16);
    uint4 o4 = {pk[0], pk[1], pk[2], pk[3]};
    *(uint4*)&wpack[(size_t)t * 8] = o4;

    if (t < 1024) {
        const int cp = t;
        const int n2 = cp & 15, g2 = (cp >> 4) & 3, w2 = (cp >> 6) & 1, cg2 = cp >> 7;
        const int h2 = cg2 * 32 + w2 * 16 + n2;
        const float* bi = (g2 == 0) ? bif : (g2 == 1) ? bii : (g2 == 2) ? bio : big;
        const float* bh = (g2 == 0) ? bhf : (g2 == 1) ? bhi : (g2 == 2) ? bho : bhg;
        bpack[cp] = bi[h2] + bh[h2];
    }
}

// ---- convert: xpack[panel(512)][step(16)][rt(8)][lane(64)][j(8)] bf16 ----
// row = panel*128 + rt*16 + (lane&15), k = step*32 + (lane>>4)*8 + j
__global__ __launch_bounds__(256) void convert_kernel(
    const float* __restrict__ input, const float* __restrict__ hidden,
    unsigned short* __restrict__ xpack)
{
    const int t = blockIdx.x * 256 + threadIdx.x;   // 0..4194303
    const int l     = t & 63;
    const int rt    = (t >> 6) & 7;
    const int step  = (t >> 9) & 15;
    const int panel = t >> 13;
    const int row = panel * 128 + rt * 16 + (l & 15);
    const int k0  = step * 32 + (l >> 4) * 8;
    const float* src = (k0 < 256) ? input + (size_t)row * 256 + k0
                                  : hidden + (size_t)row * 256 + (k0 - 256);
    float4 x0 = *(const float4*)src;
    float4 x1 = *(const float4*)(src + 4);
    uint4 o; o.x = pack2bf(x0.x, x0.y); o.y = pack2bf(x0.z, x0.w);
    o.z = pack2bf(x1.x, x1.y); o.w = pack2bf(x1.z, x1.w);
    *(uint4*)&xpack[(size_t)t * 8] = o;
}

// ---- K1: GEMM + gates. grid 4096 = 512 panels x 8 cg, block 256 (4 waves) ----
// 128x128 tile, dbuf 32KB: 4 blocks/CU. Wave (wm,wn2) owns 64 rows x 64 cols
// (cols = 4 gates x 16 h). Per step: 4 glds + 8 ds_read_b128 + 16 MFMA.
// One barrier/step: STAGE(k+1) after barrier(k) is WAR-safe (readers of the
// overwritten buffer drained their ds_reads before reaching barrier(k)).
__global__ __launch_bounds__(256, 4) void lstm_gemm_kernel(
    const unsigned short* __restrict__ xpack,
    const float* __restrict__ cell,
    const unsigned short* __restrict__ wpack, const float* __restrict__ bpack,
    float* __restrict__ out)
{
    __shared__ unsigned short buf[2][8192];   // [0..4095]=A, [4096..8191]=B

    // XCD-bijective swizzle (4096 % 8 == 0): XCD x gets panels [x*64,(x+1)*64),
    // all 8 cg-blocks of a panel on the same XCD (A reused from XCD-local L2).
    const int swz = (blockIdx.x & 7) * 512 + (blockIdx.x >> 3);
    const int cg    = swz & 7;
    const int panel = swz >> 3;
    const int row0  = panel * 128;

    const int tid = threadIdx.x;
    const int w = tid >> 6, l = tid & 63;
    const int wm = w >> 1, wn2 = w & 1;
    const int n16 = l & 15;

    const unsigned short* asrc = xpack + (size_t)panel * 65536 + l * 8;
    const unsigned short* wsrc = wpack + (size_t)cg * 65536 + l * 8;

#define STAGE(s, bb)                                                          \
    do {                                                                      \
        glds16(asrc + (size_t)(s) * 4096 + (w)     * 512, &buf[bb][(w)     * 512]); \
        glds16(asrc + (size_t)(s) * 4096 + (w + 4) * 512, &buf[bb][(w + 4) * 512]); \
        glds16(wsrc + (size_t)(s) * 4096 + (w)     * 512, &buf[bb][4096 + (w)     * 512]); \
        glds16(wsrc + (size_t)(s) * 4096 + (w + 4) * 512, &buf[bb][4096 + (w + 4) * 512]); \
    } while (0)

    STAGE(0, 0);

    f32x4 acc[4][4] = {};

#pragma unroll
    for (int k = 0; k < 16; ++k) {
        const int cb = k & 1, nb = cb ^ 1;
        asm volatile("s_waitcnt vmcnt(0)" ::: "memory");  // own S(k) landed
        __builtin_amdgcn_s_barrier();                     // all waves' S(k) landed

        short8 Af[4], Bf[4];
#pragma unroll
        for (int m = 0; m < 4; ++m)
            Af[m] = *(const short8*)&buf[cb][((wm * 4 + m) * 64 + l) << 3];
#pragma unroll
        for (int n = 0; n < 4; ++n)
            Bf[n] = *(const short8*)&buf[cb][4096 + (((wn2 * 4 + n) * 64 + l) << 3)];

        if (k < 15) STAGE(k + 1, nb);   // in flight across MFMA + next barrier

        __builtin_amdgcn_s_setprio(1);
#pragma unroll
        for (int m = 0; m < 4; ++m)
#pragma unroll
            for (int n = 0; n < 4; ++n)
                acc[m][n] = __builtin_amdgcn_mfma_f32_16x16x32_bf16(Af[m], Bf[n], acc[m][n], 0, 0, 0);
        __builtin_amdgcn_s_setprio(0);
    }
#undef STAGE

    // ---- epilogue: bias + activations + cell update ----
    const int lrow = l >> 4;
    const int hcol = cg * 32 + wn2 * 16 + n16;
    float bias[4];
#pragma unroll
    for (int n = 0; n < 4; ++n)
        bias[n] = bpack[cg * 128 + wn2 * 64 + n * 16 + n16];

#pragma unroll
    for (int m = 0; m < 4; ++m) {
#pragma unroll
        for (int rr = 0; rr < 4; ++rr) {
            const size_t rg_ = (size_t)row0 + wm * 64 + m * 16 + lrow * 4 + rr;
            const float fv = sigm(acc[m][0][rr] + bias[0]);
            const float iv = sigm(acc[m][1][rr] + bias[1]);
            const float ov = sigm(acc[m][2][rr] + bias[2]);
            const float gv = tanh_(acc[m][3][rr] + bias[3]);
            const float cv = cell[rg_ * 256 + hcol];
            const float nc = fv * cv + iv * gv;
            const float nhv = ov * tanh_(nc);
            out[(size_t)2 * BH + rg_ * 256 + hcol] = nc;
            out[(size_t)BH + rg_ * 256 + hcol] = nhv;
        }
    }
}

// ---- K2: log_softmax finalize. out[0..BH) = nh - log(sum(exp(nh))) ----
__global__ __launch_bounds__(256) void softmax_kernel(
    const float* __restrict__ nh, float* __restrict__ outp)
{
    const int w = threadIdx.x >> 6, l = threadIdx.x & 63;
#pragma unroll 1
    for (int it = 0; it < 8; ++it) {
        const size_t row = (size_t)it * 8192 + blockIdx.x * 4 + w;
        float4 v = *(const float4*)(nh + row * 256 + l * 4);
        float s = __expf(v.x) + __expf(v.y) + __expf(v.z) + __expf(v.w);
#pragma unroll
        for (int m = 1; m < 64; m <<= 1) s += __shfl_xor(s, m);
        const float lz = __logf(s);
        float4 o = {v.x - lz, v.y - lz, v.z - lz, v.w - lz};
        *(float4*)(outp + row * 256 + l * 4) = o;
    }
}

extern "C" void kernel_launch(void* const* d_in, const int* in_sizes, int n_in,
                              void* d_out, int out_size, void* d_ws, size_t ws_size,
                              hipStream_t stream)
{
    const float* input  = (const float*)d_in[0];
    const float* hidden = (const float*)d_in[1];
    const float* cell   = (const float*)d_in[2];
    const float* Wif = (const float*)d_in[3];  const float* bif = (const float*)d_in[4];
    const float* Wii = (const float*)d_in[5];  const float* bii = (const float*)d_in[6];
    const float* Wio = (const float*)d_in[7];  const float* bio = (const float*)d_in[8];
    const float* Wig = (const float*)d_in[9];  const float* big = (const float*)d_in[10];
    const float* Whf = (const float*)d_in[11]; const float* bhf = (const float*)d_in[12];
    const float* Whi = (const float*)d_in[13]; const float* bhi = (const float*)d_in[14];
    const float* Who = (const float*)d_in[15]; const float* bho = (const float*)d_in[16];
    const float* Whg = (const float*)d_in[17]; const float* bhg = (const float*)d_in[18];

    unsigned short* wpack = (unsigned short*)d_ws;                 // 1 MB
    float* bpack = (float*)((char*)d_ws + (size_t)1024 * 512 * 2); // 4 KB

    float* out = (float*)d_out;
    // xpack lives in out[0:BH) (exactly 64 MiB) — free until K2 overwrites it.
    unsigned short* xpack = (unsigned short*)d_out;

    hipLaunchKernelGGL(pack_kernel, dim3(256), dim3(256), 0, stream,
        Wif, Wii, Wio, Wig, Whf, Whi, Who, Whg,
        bif, bii, bio, big, bhf, bhi, bho, bhg, wpack, bpack);

    hipLaunchKernelGGL(convert_kernel, dim3(16384), dim3(256), 0, stream,
        input, hidden, xpack);

    hipLaunchKernelGGL(lstm_gemm_kernel, dim3(4096), dim3(256), 0, stream,
        xpack, cell, wpack, bpack, out);

    hipLaunchKernelGGL(softmax_kernel, dim3(2048), dim3(256), 0, stream,
        out + (size_t)BH, out);
}